// Round 6
// baseline (462.235 us; speedup 1.0000x reference)
//
#include <hip/hip_runtime.h>
#include <hip/hip_bf16.h>

#define LQ 30
#define LD 1024
#define EDIM 256
#define NK 11
#define NPAIR (LQ * NK)  // 330
#define SIMW 264         // 256 + 8 pad

#if __has_builtin(__builtin_amdgcn_exp2f)
#define EXP2F __builtin_amdgcn_exp2f
#else
#define EXP2F exp2f
#endif

__device__ __forceinline__ float wave_reduce_add(float v) {
#pragma unroll
  for (int o = 32; o > 0; o >>= 1) v += __shfl_xor(v, o);
  return v;
}

// mu ascending: [-0.9,-0.7,...,0.9,1.0]; sigma[0]=0.001 (pairs with mu=-0.9), else 0.1
__device__ __forceinline__ void kparams(int k, float& mu, float& w) {
  mu = (k == 10) ? 1.0f : fmaf((float)k, 0.2f, -0.9f);
  // w = -log2(e) / (2*sigma^2)
  w = (k == 0) ? -721347.52f : -72.134752f;
}

__global__ __launch_bounds__(256) void zero_pool(float* __restrict__ p, int n) {
  const int i = blockIdx.x * 256 + threadIdx.x;
  if (i < n) p[i] = 0.0f;
}

// qn[b][r][e] = l2-normalized q embeddings (coalesced float4 stores).
__global__ __launch_bounds__(256) void build_qn(
    const int* __restrict__ qidx, const float* __restrict__ emb,
    float* __restrict__ qn) {
  const int b = blockIdx.x;
  const int wave = threadIdx.x >> 6, lane = threadIdx.x & 63;
  for (int r = wave; r < LQ; r += 4) {
    const int row = qidx[b * LQ + r];
    const float4 v = *(const float4*)(emb + (size_t)row * EDIM + lane * 4);
    float ss = v.x * v.x + v.y * v.y + v.z * v.z + v.w * v.w;
    ss = wave_reduce_add(ss);
    const float inv = rsqrtf(fmaxf(ss, 1e-12f));
    float4 o;
    o.x = v.x * inv; o.y = v.y * inv; o.z = v.z * inv; o.w = v.w * inv;
    *(float4*)(qn + ((size_t)b * LQ + r) * EDIM + lane * 4) = o;
  }
}

// Main: one block per (batch, 256-doc chunk). 1 doc per thread.
__global__ __launch_bounds__(256, 4) void knrm_part(
    const int* __restrict__ didx, const float* __restrict__ emb,
    const float* __restrict__ qn, float* __restrict__ pool_g) {
  const int b = blockIdx.x >> 2;
  const int blk = blockIdx.x & 3;
  const int tid = threadIdx.x;

  __shared__ float sim[LQ][SIMW];

  // ---------------- phase A: sim for this thread's doc ----------------
  {
    const int row = didx[b * LD + blk * 256 + tid];
    const float* dbase = emb + (size_t)row * EDIM;
    const float* qb = qn + (size_t)b * LQ * EDIM;  // wave-uniform base
    float acc[LQ];
#pragma unroll
    for (int q2 = 0; q2 < LQ; ++q2) acc[q2] = 0.0f;
    float ss = 0.0f;
    for (int ec = 0; ec < EDIM; ec += 16) {
      float4 dv[4];
#pragma unroll
      for (int i = 0; i < 4; ++i) dv[i] = *(const float4*)(dbase + ec + i * 4);
      float v[16];
#pragma unroll
      for (int i = 0; i < 4; ++i) {
        v[i * 4 + 0] = dv[i].x; v[i * 4 + 1] = dv[i].y;
        v[i * 4 + 2] = dv[i].z; v[i * 4 + 3] = dv[i].w;
      }
#pragma unroll
      for (int e = 0; e < 16; ++e) ss = fmaf(v[e], v[e], ss);
#pragma unroll
      for (int q2 = 0; q2 < LQ; ++q2) {
        const float* qrow = qb + q2 * EDIM + ec;  // uniform -> s_load
#pragma unroll
        for (int e = 0; e < 16; ++e) acc[q2] = fmaf(v[e], qrow[e], acc[q2]);
      }
    }
    const float inv = rsqrtf(fmaxf(ss, 1e-12f));
#pragma unroll
    for (int q2 = 0; q2 < LQ; ++q2) sim[q2][tid] = acc[q2] * inv;
  }
  __syncthreads();

  // ------- phase B: exp pooling (660 items = 330 pairs x 2 chunks of 128) -----
  // Direct global atomic per item: <=8 adds per pool_g address total (4 blocks
  // x 2 chunks) -> negligible contention; avoids any blockDim>=NPAIR assumption.
#pragma unroll
  for (int it = 0; it < 3; ++it) {
    const int item = tid + it * 256;
    if (item < NPAIR * 2) {
      const int chunk = item / NPAIR;
      const int pr = item - chunk * NPAIR;
      const int q2 = pr / NK;
      const int k = pr - q2 * NK;
      float mu, w;
      kparams(k, mu, w);
      const float* srow = &sim[q2][chunk * 128];
      float lacc = 0.0f;
#pragma unroll 8
      for (int j = 0; j < 128; j += 4) {
        const float4 s4 = *(const float4*)(srow + j);
        { const float u = s4.x - mu; lacc += EXP2F(u * u * w); }
        { const float u = s4.y - mu; lacc += EXP2F(u * u * w); }
        { const float u = s4.z - mu; lacc += EXP2F(u * u * w); }
        { const float u = s4.w - mu; lacc += EXP2F(u * u * w); }
      }
      atomicAdd(&pool_g[b * NPAIR + pr], lacc);
    }
  }
}

// Finalize: log, weight, reduce -> out[b]
__global__ __launch_bounds__(64) void knrm_fin(
    const float* __restrict__ pool_g, const float* __restrict__ W,
    const float* __restrict__ bptr, float* __restrict__ out) {
  const int b = blockIdx.x;
  const int t = threadIdx.x;
  float v = 0.0f;
  for (int pr = t; pr < NPAIR; pr += 64) {
    const int q2 = pr / NK;
    const int k = pr - q2 * NK;
    v += logf(fmaxf(pool_g[b * NPAIR + pr], 1e-10f)) * 0.01f * W[k];
  }
  v = wave_reduce_add(v);
  if (t == 0) out[b] = v + bptr[0];
}

// ---------------- fallback (no workspace): round-2 kernel (512 thr) ----------
__global__ __launch_bounds__(512) void knrm_mono(
    const int* __restrict__ qidx, const int* __restrict__ didx,
    const float* __restrict__ emb, const float* __restrict__ W,
    const float* __restrict__ bptr, float* __restrict__ out) {
  constexpr int PASS_D = 256;
  constexpr int SW = PASS_D + 8;
  constexpr int NITEM = NPAIR * 2;
  constexpr int QBF_STRIDE = 40;
  const int b = blockIdx.x;
  const int tid = threadIdx.x;
  const int wave = tid >> 6, lane = tid & 63;
  __shared__ float sim[LQ][SW];
  __shared__ float pool[NPAIR];
  __shared__ float red[8];
  __shared__ unsigned short qbf[EDIM * QBF_STRIDE];
  if (tid < NPAIR) pool[tid] = 0.0f;
  for (int r = wave; r < LQ; r += 8) {
    const int row = qidx[b * LQ + r];
    const float4 v = *(const float4*)(emb + (size_t)row * EDIM + lane * 4);
    float ss = v.x * v.x + v.y * v.y + v.z * v.z + v.w * v.w;
    ss = wave_reduce_add(ss);
    const float inv = rsqrtf(fmaxf(ss, 1e-12f));
    const float vals[4] = {v.x * inv, v.y * inv, v.z * inv, v.w * inv};
#pragma unroll
    for (int j = 0; j < 4; ++j) {
      unsigned u = __float_as_uint(vals[j]);
      unsigned rr = (u + 0x7FFFu + ((u >> 16) & 1u)) >> 16;
      qbf[(lane * 4 + j) * QBF_STRIDE + r] = (unsigned short)rr;
    }
  }
  __syncthreads();
  float part[2] = {0.0f, 0.0f};
  for (int pass = 0; pass < 4; ++pass) {
    if (tid < PASS_D) {
      const int row = didx[b * LD + pass * PASS_D + tid];
      const float* dbase = emb + (size_t)row * EDIM;
      float acc[LQ];
#pragma unroll
      for (int q2 = 0; q2 < LQ; ++q2) acc[q2] = 0.0f;
      float ss = 0.0f;
      for (int ec = 0; ec < EDIM; ec += 16) {
        float4 dv[4];
#pragma unroll
        for (int i = 0; i < 4; ++i) dv[i] = *(const float4*)(dbase + ec + i * 4);
#pragma unroll
        for (int i = 0; i < 4; ++i) {
          const float vv[4] = {dv[i].x, dv[i].y, dv[i].z, dv[i].w};
#pragma unroll
          for (int c = 0; c < 4; ++c) {
            const int e = ec + i * 4 + c;
            const float v = vv[c];
            ss = fmaf(v, v, ss);
            const unsigned short* qe = &qbf[e * QBF_STRIDE];
#pragma unroll
            for (int q2 = 0; q2 < LQ; ++q2) {
              const float qv = __uint_as_float(((unsigned)qe[q2]) << 16);
              acc[q2] = fmaf(v, qv, acc[q2]);
            }
          }
        }
      }
      const float inv = rsqrtf(fmaxf(ss, 1e-12f));
#pragma unroll
      for (int q2 = 0; q2 < LQ; ++q2) sim[q2][tid] = acc[q2] * inv;
    }
    __syncthreads();
#pragma unroll
    for (int it = 0; it < 2; ++it) {
      const int item = tid + it * 512;
      if (item < NITEM) {
        const int chunk = item / NPAIR;
        const int pr = item - chunk * NPAIR;
        const int q2 = pr / NK;
        const int k = pr - q2 * NK;
        float mu, w;
        kparams(k, mu, w);
        const float* srow = &sim[q2][chunk * 128];
        float lacc = 0.0f;
#pragma unroll 8
        for (int j = 0; j < 128; j += 4) {
          const float4 s4 = *(const float4*)(srow + j);
          { const float u = s4.x - mu; lacc += EXP2F(u * u * w); }
          { const float u = s4.y - mu; lacc += EXP2F(u * u * w); }
          { const float u = s4.z - mu; lacc += EXP2F(u * u * w); }
          { const float u = s4.w - mu; lacc += EXP2F(u * u * w); }
        }
        part[it] += lacc;
      }
    }
    __syncthreads();
  }
#pragma unroll
  for (int it = 0; it < 2; ++it) {
    const int item = tid + it * 512;
    if (item < NITEM) {
      const int pr = item % NPAIR;
      atomicAdd(&pool[pr], part[it]);
    }
  }
  __syncthreads();
  float v = 0.0f;
  if (tid < NPAIR) {
    const int k = tid % NK;
    v = logf(fmaxf(pool[tid], 1e-10f)) * 0.01f * W[k];
  }
  v = wave_reduce_add(v);
  if (lane == 0) red[wave] = v;
  __syncthreads();
  if (tid == 0) {
    float t = 0.0f;
#pragma unroll
    for (int w2 = 0; w2 < 8; ++w2) t += red[w2];
    out[b] = t + bptr[0];
  }
}

extern "C" void kernel_launch(void* const* d_in, const int* in_sizes, int n_in,
                              void* d_out, int out_size, void* d_ws, size_t ws_size,
                              hipStream_t stream) {
  (void)n_in;
  (void)out_size;
  const int* qidx = (const int*)d_in[0];
  const int* didx = (const int*)d_in[1];
  const float* emb = (const float*)d_in[2];
  const float* W = (const float*)d_in[3];
  const float* bptr = (const float*)d_in[4];
  float* out = (float*)d_out;

  const int B = in_sizes[0] / LQ;  // 256
  const size_t qn_bytes = (size_t)B * LQ * EDIM * sizeof(float);      // 7.86 MB
  const size_t pool_bytes = (size_t)B * NPAIR * sizeof(float);        // 338 KB

  if (ws_size >= qn_bytes + pool_bytes) {
    float* qn = (float*)d_ws;
    float* pool_g = (float*)((char*)d_ws + qn_bytes);
    const int pool_n = B * NPAIR;
    zero_pool<<<(pool_n + 255) / 256, 256, 0, stream>>>(pool_g, pool_n);
    build_qn<<<B, 256, 0, stream>>>(qidx, emb, qn);
    knrm_part<<<B * 4, 256, 0, stream>>>(didx, emb, qn, pool_g);
    knrm_fin<<<B, 64, 0, stream>>>(pool_g, W, bptr, out);
  } else {
    knrm_mono<<<B, 512, 0, stream>>>(qidx, didx, emb, W, bptr, out);
  }
}